// Round 10
// baseline (429.410 us; speedup 1.0000x reference)
//
#include <hip/hip_runtime.h>
#include <hip/hip_bf16.h>

// Problem constants
#define TT 512   // T
#define BB 128   // B
#define HH 512   // H
#define NFC 128  // NF
// FS = 5

typedef short v8s __attribute__((ext_vector_type(8)));
typedef float v4f __attribute__((ext_vector_type(4)));

__device__ __forceinline__ unsigned short f2bf(float x) {
    unsigned u = __float_as_uint(x);
    unsigned r = (u + 0x7fffu + ((u >> 16) & 1u)) >> 16;
    return (unsigned short)r;
}

// ---------------------------------------------------------------------------
// Kernel 0: fused prep + gather.
// blocks [0,8192): gather X_all, [n][h] bf16, n=b*512+l; skip unread tiles.
// blocks [8192,12288): build stacked weight Wg, bf16, M=2048 x K=512.
// blocks [12288,12608): zero pools.
// block 12608: collapse fc2∘fc1 into v[640] + c.
// block 12609: parallel worklist of active (b,tt) items (unordered).
// ---------------------------------------------------------------------------
__global__ void prep_all(const float* __restrict__ enc, const int* __restrict__ lengths,
                         unsigned short* __restrict__ Xg,
                         const float* __restrict__ w1, const float* __restrict__ w2,
                         const float* __restrict__ w3, const float* __restrict__ w4,
                         const float* __restrict__ w5, unsigned short* __restrict__ Wg,
                         float* __restrict__ pools,
                         const float* __restrict__ fc1w, const float* __restrict__ fc1b,
                         const float* __restrict__ fc2w, const float* __restrict__ fc2b,
                         float* __restrict__ v, int* __restrict__ wl) {
    int blk = blockIdx.x;
    int tid = threadIdx.x;
    if (blk < 8192) {
        __shared__ float tile[64 * 65];
        int b = blk >> 6;
        int lc = (blk >> 3) & 7;
        int hc = blk & 7;
        int L = lengths[b];
        int Leff = L > 5 ? L : 5;
        int l0 = lc * 64, h0 = hc * 64;
        if (l0 >= Leff + 127) return;     // never read by any active tile
        int lx = tid & 63;
        int hq = tid >> 6;                // 0..3
        #pragma unroll
        for (int r = 0; r < 16; ++r) {
            int hl = hq * 16 + r;         // local h
            int l = l0 + lx;
            float val = 0.f;
            if (l < L) {
                int i = (h0 + hl) * L + l;
                val = enc[(i >> 9) * (BB * HH) + b * HH + (i & 511)];
            }
            tile[hl * 65 + lx] = val;
        }
        __syncthreads();
        int hg = tid & 15;                // h quad within tile (4 bf16 = 8B)
        #pragma unroll
        for (int r = 0; r < 4; ++r) {
            int lloc = (tid >> 4) + r * 16;
            int n = b * 512 + l0 + lloc;
            ushort4 pk;
            pk.x = f2bf(tile[(hg * 4 + 0) * 65 + lloc]);
            pk.y = f2bf(tile[(hg * 4 + 1) * 65 + lloc]);
            pk.z = f2bf(tile[(hg * 4 + 2) * 65 + lloc]);
            pk.w = f2bf(tile[(hg * 4 + 3) * 65 + lloc]);
            *(ushort4*)&Xg[n * 512 + h0 + hg * 4] = pk;
        }
    } else if (blk < 12288) {
        int idx = (blk - 8192) * 256 + tid;   // 2048*512 = 1,048,576
        int s = idx >> 9, h = idx & 511;
        int f = s >> 4, sl = s & 15;
        float val = 0.f;
        if (sl < 15) {
            int w, j;
            if (sl < 1)       { w = 1; j = sl; }
            else if (sl < 3)  { w = 2; j = sl - 1; }
            else if (sl < 6)  { w = 3; j = sl - 3; }
            else if (sl < 10) { w = 4; j = sl - 6; }
            else              { w = 5; j = sl - 10; }
            const float* wp = (w == 1) ? w1 : (w == 2) ? w2 : (w == 3) ? w3 : (w == 4) ? w4 : w5;
            val = wp[f * (HH * w) + h * w + j];  // conv_w{w}[f,0,h,j]
        }
        Wg[idx] = f2bf(val);
    } else if (blk < 12608) {
        int i = (blk - 12288) * 256 + tid;
        if (i < BB * 5 * NFC) pools[i] = 0.f;
    } else if (blk == 12608) {
        for (int k = tid; k < 640; k += 256) {
            float s = 0.f;
            for (int o = 0; o < 100; ++o) s += fc2w[o] * fc1w[o * 640 + k];
            v[k] = s;
        }
        if (tid == 0) {
            float c = fc2b[0];
            for (int o = 0; o < 100; ++o) c += fc2w[o] * fc1b[o];
            v[640] = c;
        }
    } else {
        __shared__ int cnt;
        if (tid == 0) cnt = 0;
        __syncthreads();
        for (int it = tid; it < 640; it += 256) {
            int b = it / 5, tt = it % 5;
            int L = lengths[b];
            int Leff = L > 5 ? L : 5;
            int n0 = tt * 124 - ((tt >> 2) * 112);   // {0,124,248,372,384}
            if (n0 < Leff) {
                int pos = atomicAdd(&cnt, 1);
                wl[pos] = (b << 3) | tt;
            }
        }
        __syncthreads();
        if (tid == 0) wl[640] = cnt;
    }
}

// ---------------------------------------------------------------------------
// Kernel 1: main fused GEMM + epilogue.
// Round-9 single-barrier double-buffered K-loop, with LDS trimmed to exactly
// 32 KB so 5 blocks/CU fit (160 KB / 32 KB): epilogue Gs shrunk to 32x129 f32
// (16.5 KB, aliases the dbuf region) -> 4 phases of 32 rows instead of 2x64.
// 20 waves/CU (was 16) for latency hiding; measured 148 us vs ~84 us LDS
// floor was stall-dominated.
// Grid: (640, 16). x = compacted work item (b,tt), y = mt (128-row M-slab).
// Block tile 128x128, BK=32; 4 waves as 2x2, wave tile 64x64 (acc 4x4).
// One barrier per K-iter: stage(kt+1) into the other buffer issued before
// the MFMA block of iter kt; end-of-iter __syncthreads drains it and closes
// the WAR window (buffers alternate).
// Lesson (r6/r8): ALL global traffic via global_load_lds; never per-lane
// global loads in the MFMA chain.
// Overlapped column tiles n0 in {0,124,248,372,384} (no strips/cleanup).
// Swizzle: physical 16B chunk p = q ^ ((row>>1)&3); staging permutes the
// GLOBAL address (LDS dest lane-contiguous, m104); frag reads 2-way (free).
// Spill tripwire: epilogue acc indices all compile-time; WRITE_SIZE ~6.9 MB.
// ---------------------------------------------------------------------------
__global__ __launch_bounds__(256, 5)
void conv_gemm(const unsigned short* __restrict__ Wg, const unsigned short* __restrict__ Xg,
               const int* __restrict__ lengths, const int* __restrict__ wl,
               const float* __restrict__ cb1, const float* __restrict__ cb2,
               const float* __restrict__ cb3, const float* __restrict__ cb4,
               const float* __restrict__ cb5,
               float* __restrict__ pools) {
    __shared__ __align__(16) char smem[32768];               // exactly 32 KB -> 5 blocks/CU
    unsigned short* ldsA = (unsigned short*)smem;            // 2 x 4096 ushorts (dbuf)
    unsigned short* ldsB = (unsigned short*)(smem + 16384);  // 2 x 4096 ushorts (dbuf)
    float* Gs = (float*)smem;                                // 32 x 129 f32 (epilogue only)

    int cnt = wl[640];
    int wk = blockIdx.x;
    if (wk >= cnt) return;
    int item = wl[wk];
    int b = item >> 3, tt = item & 7;
    int mt = blockIdx.y;
    int n0 = tt * 124 - ((tt >> 2) * 112);   // {0,124,248,372,384}
    int L = lengths[b];
    int Leff = L > 5 ? L : 5;

    int tid = threadIdx.x;
    int wid = tid >> 6, lane = tid & 63;
    int wm = wid >> 1, wn = wid & 1;
    int llo = lane & 15, quad = lane >> 4;
    int psw = quad ^ ((llo >> 1) & 3);   // swizzled physical chunk for frag reads

    int m0 = mt * 128;
    int nb0 = b * 512 + n0;

    v4f acc[4][4];
    #pragma unroll
    for (int i = 0; i < 4; ++i)
        #pragma unroll
        for (int j = 0; j < 4; ++j) acc[i][j] = v4f{0.f, 0.f, 0.f, 0.f};

    // staging: wave wid covers rows [wid*32, wid*32+32) in 2 insts of 16 rows
    int srow = lane >> 2;                           // 0..15
    int gchunk = (lane & 3) ^ ((lane >> 3) & 3);    // global chunk for physical slot lane&3
    const unsigned short* gA = Wg + (m0 + wid * 32 + srow) * 512 + gchunk * 8;
    const unsigned short* gB = Xg + (nb0 + wid * 32 + srow) * 512 + gchunk * 8;
    int sdst = (wid * 32) * 32;   // ushort offset of this wave's staging rows

    // prologue: stage k-tile 0 into buffer 0
    #pragma unroll
    for (int q = 0; q < 2; ++q) {
        __builtin_amdgcn_global_load_lds(
            (const __attribute__((address_space(1))) unsigned int*)(gA + q * (16 * 512)),
            (__attribute__((address_space(3))) unsigned int*)&ldsA[sdst + q * 512],
            16, 0, 0);
        __builtin_amdgcn_global_load_lds(
            (const __attribute__((address_space(1))) unsigned int*)(gB + q * (16 * 512)),
            (__attribute__((address_space(3))) unsigned int*)&ldsB[sdst + q * 512],
            16, 0, 0);
    }
    __syncthreads();

    #pragma unroll 1
    for (int kt = 0; kt < 16; ++kt) {
        // issue next-iter staging into the other buffer (overlaps this MFMA)
        if (kt < 15) {
            int ko = (kt + 1) * 32;
            int bb = ((kt + 1) & 1) * 4096;
            #pragma unroll
            for (int q = 0; q < 2; ++q) {
                __builtin_amdgcn_global_load_lds(
                    (const __attribute__((address_space(1))) unsigned int*)(gA + q * (16 * 512) + ko),
                    (__attribute__((address_space(3))) unsigned int*)&ldsA[bb + sdst + q * 512],
                    16, 0, 0);
                __builtin_amdgcn_global_load_lds(
                    (const __attribute__((address_space(1))) unsigned int*)(gB + q * (16 * 512) + ko),
                    (__attribute__((address_space(3))) unsigned int*)&ldsB[bb + sdst + q * 512],
                    16, 0, 0);
            }
        }
        int boff = (kt & 1) * 4096;
        v8s Af[4], Bf[4];
        #pragma unroll
        for (int mi = 0; mi < 4; ++mi)
            Af[mi] = *(const v8s*)&ldsA[boff + (wm * 64 + mi * 16 + llo) * 32 + psw * 8];
        #pragma unroll
        for (int ni = 0; ni < 4; ++ni)
            Bf[ni] = *(const v8s*)&ldsB[boff + (wn * 64 + ni * 16 + llo) * 32 + psw * 8];
        #pragma unroll
        for (int mi = 0; mi < 4; ++mi)
            #pragma unroll
            for (int ni = 0; ni < 4; ++ni)
                acc[mi][ni] = __builtin_amdgcn_mfma_f32_16x16x32_bf16(Af[mi], Bf[ni], acc[mi][ni], 0, 0, 0);
        __syncthreads();   // drains stage(kt+1); closes WAR window on buffers
    }

    // ---- epilogue: 4 phases of 32 rows (2 filter groups each) ----
    // phase p covers global rows [32p, 32p+32) = acc rows of wave wm = p>>1,
    // mi = (p&1)*2 + {0,1}. All indices compile-time (spill tripwire).
    const int basew[6] = {0, 0, 1, 3, 6, 10};
    int fg = wid & 1, half = wid >> 1;
    int tcol = half * 64 + lane;

    #pragma unroll
    for (int p = 0; p < 4; ++p) {
        if (wm == (p >> 1)) {
            // C/D layout: col = lane&15, row = quad*4 + reg  [verified m89/m91]
            #pragma unroll
            for (int mi2 = 0; mi2 < 2; ++mi2)
                #pragma unroll
                for (int ni = 0; ni < 4; ++ni)
                    #pragma unroll
                    for (int r = 0; r < 4; ++r)
                        Gs[(mi2 * 16 + quad * 4 + r) * 129 + wn * 64 + ni * 16 + llo] =
                            acc[(p & 1) * 2 + mi2][ni][r];
        }
        __syncthreads();
        // pooling: wave wid -> filter group fg of this phase, t-half
        {
            int f = mt * 8 + p * 2 + fg;
            #pragma unroll
            for (int w = 1; w <= 5; ++w) {
                float bias = (w == 1 ? cb1 : w == 2 ? cb2 : w == 3 ? cb3 : w == 4 ? cb4 : cb5)[f];
                int limv = Leff - w + 1 - n0;          // tile-local validity bound
                float vmax = -1.f;
                if (tcol <= 128 - w && tcol < limv) {
                    float s = 0.f;
                    #pragma unroll
                    for (int j = 0; j < w; ++j)
                        s += Gs[(fg * 16 + basew[w] + j) * 129 + tcol + j];
                    s += bias;
                    vmax = fmaxf(s, 0.f);
                }
                #pragma unroll
                for (int off = 32; off >= 1; off >>= 1)
                    vmax = fmaxf(vmax, __shfl_xor(vmax, off));
                if (lane == 0 && vmax >= 0.f)
                    atomicMax((int*)&pools[(b * 5 + (w - 1)) * NFC + f], __float_as_int(vmax));
            }
        }
        __syncthreads();
    }
}

// ---------------------------------------------------------------------------
// Kernel 2: per-batch dot(feat, v) + c -> sigmoid.
// feat[b][k] = pools[b][w][f] with k = w*128+f (matches concat order).
// ---------------------------------------------------------------------------
__global__ void head(const float* __restrict__ pools, const float* __restrict__ v,
                     float* __restrict__ out) {
    int b = blockIdx.x;
    int tid = threadIdx.x;
    float s = 0.f;
    for (int k = tid; k < 640; k += 256) s += pools[b * 640 + k] * v[k];
    __shared__ float red[256];
    red[tid] = s;
    __syncthreads();
    for (int st = 128; st; st >>= 1) {
        if (tid < st) red[tid] += red[tid + st];
        __syncthreads();
    }
    if (tid == 0) out[b] = 1.f / (1.f + expf(-(red[0] + v[640])));
}

// ---------------------------------------------------------------------------
extern "C" void kernel_launch(void* const* d_in, const int* in_sizes, int n_in,
                              void* d_out, int out_size, void* d_ws, size_t ws_size,
                              hipStream_t stream) {
    const float* enc  = (const float*)d_in[0];
    const int* lens   = (const int*)d_in[1];
    const float* w1   = (const float*)d_in[2];
    const float* b1   = (const float*)d_in[3];
    const float* w2   = (const float*)d_in[4];
    const float* b2   = (const float*)d_in[5];
    const float* w3   = (const float*)d_in[6];
    const float* b3   = (const float*)d_in[7];
    const float* w4   = (const float*)d_in[8];
    const float* b4   = (const float*)d_in[9];
    const float* w5   = (const float*)d_in[10];
    const float* b5   = (const float*)d_in[11];
    const float* fc1w = (const float*)d_in[12];
    const float* fc1b = (const float*)d_in[13];
    const float* fc2w = (const float*)d_in[14];
    const float* fc2b = (const float*)d_in[15];
    float* out = (float*)d_out;

    // workspace layout
    unsigned short* Xg = (unsigned short*)d_ws;          // 33,554,432 ushorts (64 MB)
    unsigned short* Wg = Xg + 33554432;                  // 1,048,576 ushorts (2 MB)
    float* pools  = (float*)(Wg + 1048576);              // 81,920 floats
    float* vbuf   = pools + 81920;                       // 641 floats
    int* wlist    = (int*)(vbuf + 641);                  // 641 ints

    prep_all<<<12610, 256, 0, stream>>>(enc, lens, Xg, w1, w2, w3, w4, w5, Wg, pools,
                                        fc1w, fc1b, fc2w, fc2b, vbuf, wlist);
    conv_gemm<<<dim3(640, 16), 256, 0, stream>>>(Wg, Xg, lens, wlist, b1, b2, b3, b4, b5, pools);
    head<<<128, 256, 0, stream>>>(pools, vbuf, out);
}

// Round 11
// 370.993 us; speedup vs baseline: 1.1575x; 1.1575x over previous
//
#include <hip/hip_runtime.h>
#include <hip/hip_bf16.h>

// Problem constants
#define TT 512   // T
#define BB 128   // B
#define HH 512   // H
#define NFC 128  // NF
// FS = 5

typedef short v8s __attribute__((ext_vector_type(8)));
typedef float v4f __attribute__((ext_vector_type(4)));

__device__ __forceinline__ unsigned short f2bf(float x) {
    unsigned u = __float_as_uint(x);
    unsigned r = (u + 0x7fffu + ((u >> 16) & 1u)) >> 16;
    return (unsigned short)r;
}

// ---------------------------------------------------------------------------
// Kernel 0: fused prep + gather.
// blocks [0,8192): gather X_all, [n][h] bf16, n=b*512+l; skip unread tiles.
// blocks [8192,12288): build stacked weight Wg, bf16, M=2048 x K=512.
// blocks [12288,12608): zero pools.
// block 12608: collapse fc2∘fc1 into v[640] + c.
// block 12609: parallel worklist of active (b,tt) items (unordered).
// ---------------------------------------------------------------------------
__global__ void prep_all(const float* __restrict__ enc, const int* __restrict__ lengths,
                         unsigned short* __restrict__ Xg,
                         const float* __restrict__ w1, const float* __restrict__ w2,
                         const float* __restrict__ w3, const float* __restrict__ w4,
                         const float* __restrict__ w5, unsigned short* __restrict__ Wg,
                         float* __restrict__ pools,
                         const float* __restrict__ fc1w, const float* __restrict__ fc1b,
                         const float* __restrict__ fc2w, const float* __restrict__ fc2b,
                         float* __restrict__ v, int* __restrict__ wl) {
    int blk = blockIdx.x;
    int tid = threadIdx.x;
    if (blk < 8192) {
        __shared__ float tile[64 * 65];
        int b = blk >> 6;
        int lc = (blk >> 3) & 7;
        int hc = blk & 7;
        int L = lengths[b];
        int Leff = L > 5 ? L : 5;
        int l0 = lc * 64, h0 = hc * 64;
        if (l0 >= Leff + 127) return;     // never read by any active tile
        int lx = tid & 63;
        int hq = tid >> 6;                // 0..3
        #pragma unroll
        for (int r = 0; r < 16; ++r) {
            int hl = hq * 16 + r;         // local h
            int l = l0 + lx;
            float val = 0.f;
            if (l < L) {
                int i = (h0 + hl) * L + l;
                val = enc[(i >> 9) * (BB * HH) + b * HH + (i & 511)];
            }
            tile[hl * 65 + lx] = val;
        }
        __syncthreads();
        int hg = tid & 15;                // h quad within tile (4 bf16 = 8B)
        #pragma unroll
        for (int r = 0; r < 4; ++r) {
            int lloc = (tid >> 4) + r * 16;
            int n = b * 512 + l0 + lloc;
            ushort4 pk;
            pk.x = f2bf(tile[(hg * 4 + 0) * 65 + lloc]);
            pk.y = f2bf(tile[(hg * 4 + 1) * 65 + lloc]);
            pk.z = f2bf(tile[(hg * 4 + 2) * 65 + lloc]);
            pk.w = f2bf(tile[(hg * 4 + 3) * 65 + lloc]);
            *(ushort4*)&Xg[n * 512 + h0 + hg * 4] = pk;
        }
    } else if (blk < 12288) {
        int idx = (blk - 8192) * 256 + tid;   // 2048*512 = 1,048,576
        int s = idx >> 9, h = idx & 511;
        int f = s >> 4, sl = s & 15;
        float val = 0.f;
        if (sl < 15) {
            int w, j;
            if (sl < 1)       { w = 1; j = sl; }
            else if (sl < 3)  { w = 2; j = sl - 1; }
            else if (sl < 6)  { w = 3; j = sl - 3; }
            else if (sl < 10) { w = 4; j = sl - 6; }
            else              { w = 5; j = sl - 10; }
            const float* wp = (w == 1) ? w1 : (w == 2) ? w2 : (w == 3) ? w3 : (w == 4) ? w4 : w5;
            val = wp[f * (HH * w) + h * w + j];  // conv_w{w}[f,0,h,j]
        }
        Wg[idx] = f2bf(val);
    } else if (blk < 12608) {
        int i = (blk - 12288) * 256 + tid;
        if (i < BB * 5 * NFC) pools[i] = 0.f;
    } else if (blk == 12608) {
        for (int k = tid; k < 640; k += 256) {
            float s = 0.f;
            for (int o = 0; o < 100; ++o) s += fc2w[o] * fc1w[o * 640 + k];
            v[k] = s;
        }
        if (tid == 0) {
            float c = fc2b[0];
            for (int o = 0; o < 100; ++o) c += fc2w[o] * fc1b[o];
            v[640] = c;
        }
    } else {
        __shared__ int cnt;
        if (tid == 0) cnt = 0;
        __syncthreads();
        for (int it = tid; it < 640; it += 256) {
            int b = it / 5, tt = it % 5;
            int L = lengths[b];
            int Leff = L > 5 ? L : 5;
            int n0 = tt * 124 - ((tt >> 2) * 112);   // {0,124,248,372,384}
            if (n0 < Leff) {
                int pos = atomicAdd(&cnt, 1);
                wl[pos] = (b << 3) | tt;
            }
        }
        __syncthreads();
        if (tid == 0) wl[640] = cnt;
    }
}

// ---------------------------------------------------------------------------
// Kernel 1: main fused GEMM + epilogue. EXACT round-9 structure (best: 148us)
// with ONE change: grid transposed to (16, 640) — blockIdx.x = mt (fast),
// blockIdx.y = work item. The 16 mt-siblings sharing one item's 128 KB
// B-slab now dispatch consecutively -> B served hot from L2/L3 instead of
// re-streamed from HBM (r9 FETCH was 220 MB vs ~49 MB compulsory).
// r10 lesson: register floor of this loop is ~120 (64 acc + ~56 arch), so
// 4 waves/SIMD is the max — launch_bounds stays (256,4), LDS 33 KB.
// Single-barrier double-buffered K-loop: stage(kt+1) into the other buffer
// before MFMA(kt); end-of-iter __syncthreads drains + closes WAR.
// All global traffic via global_load_lds (r6/r8: per-lane loads in the MFMA
// chain lose). Overlapped column tiles n0 in {0,124,248,372,384}.
// Swizzle: physical 16B chunk p = q ^ ((row>>1)&3); staging permutes the
// GLOBAL address (LDS dest lane-contiguous, m104); frag reads 2-way (free).
// ---------------------------------------------------------------------------
__global__ __launch_bounds__(256, 4)
void conv_gemm(const unsigned short* __restrict__ Wg, const unsigned short* __restrict__ Xg,
               const int* __restrict__ lengths, const int* __restrict__ wl,
               const float* __restrict__ cb1, const float* __restrict__ cb2,
               const float* __restrict__ cb3, const float* __restrict__ cb4,
               const float* __restrict__ cb5,
               float* __restrict__ pools) {
    __shared__ __align__(16) char smem[64 * 129 * 4];       // 33024 B
    unsigned short* ldsA = (unsigned short*)smem;            // 2 x 4096 ushorts (dbuf)
    unsigned short* ldsB = (unsigned short*)(smem + 16384);  // 2 x 4096 ushorts (dbuf)
    float* Gs = (float*)smem;                                // 64*129 (epilogue only)

    int cnt = wl[640];
    int wk = blockIdx.y;
    if (wk >= cnt) return;
    int item = wl[wk];
    int b = item >> 3, tt = item & 7;
    int mt = blockIdx.x;
    int n0 = tt * 124 - ((tt >> 2) * 112);   // {0,124,248,372,384}
    int L = lengths[b];
    int Leff = L > 5 ? L : 5;

    int tid = threadIdx.x;
    int wid = tid >> 6, lane = tid & 63;
    int wm = wid >> 1, wn = wid & 1;
    int llo = lane & 15, quad = lane >> 4;
    int psw = quad ^ ((llo >> 1) & 3);   // swizzled physical chunk for frag reads

    int m0 = mt * 128;
    int nb0 = b * 512 + n0;

    v4f acc[4][4];
    #pragma unroll
    for (int i = 0; i < 4; ++i)
        #pragma unroll
        for (int j = 0; j < 4; ++j) acc[i][j] = v4f{0.f, 0.f, 0.f, 0.f};

    // staging: wave wid covers rows [wid*32, wid*32+32) in 2 insts of 16 rows
    int srow = lane >> 2;                           // 0..15
    int gchunk = (lane & 3) ^ ((lane >> 3) & 3);    // global chunk for physical slot lane&3
    const unsigned short* gA = Wg + (m0 + wid * 32 + srow) * 512 + gchunk * 8;
    const unsigned short* gB = Xg + (nb0 + wid * 32 + srow) * 512 + gchunk * 8;
    int sdst = (wid * 32) * 32;   // ushort offset of this wave's staging rows

    // prologue: stage k-tile 0 into buffer 0
    #pragma unroll
    for (int q = 0; q < 2; ++q) {
        __builtin_amdgcn_global_load_lds(
            (const __attribute__((address_space(1))) unsigned int*)(gA + q * (16 * 512)),
            (__attribute__((address_space(3))) unsigned int*)&ldsA[sdst + q * 512],
            16, 0, 0);
        __builtin_amdgcn_global_load_lds(
            (const __attribute__((address_space(1))) unsigned int*)(gB + q * (16 * 512)),
            (__attribute__((address_space(3))) unsigned int*)&ldsB[sdst + q * 512],
            16, 0, 0);
    }
    __syncthreads();

    #pragma unroll 1
    for (int kt = 0; kt < 16; ++kt) {
        // issue next-iter staging into the other buffer (overlaps this MFMA)
        if (kt < 15) {
            int ko = (kt + 1) * 32;
            int bb = ((kt + 1) & 1) * 4096;
            #pragma unroll
            for (int q = 0; q < 2; ++q) {
                __builtin_amdgcn_global_load_lds(
                    (const __attribute__((address_space(1))) unsigned int*)(gA + q * (16 * 512) + ko),
                    (__attribute__((address_space(3))) unsigned int*)&ldsA[bb + sdst + q * 512],
                    16, 0, 0);
                __builtin_amdgcn_global_load_lds(
                    (const __attribute__((address_space(1))) unsigned int*)(gB + q * (16 * 512) + ko),
                    (__attribute__((address_space(3))) unsigned int*)&ldsB[bb + sdst + q * 512],
                    16, 0, 0);
            }
        }
        int boff = (kt & 1) * 4096;
        v8s Af[4], Bf[4];
        #pragma unroll
        for (int mi = 0; mi < 4; ++mi)
            Af[mi] = *(const v8s*)&ldsA[boff + (wm * 64 + mi * 16 + llo) * 32 + psw * 8];
        #pragma unroll
        for (int ni = 0; ni < 4; ++ni)
            Bf[ni] = *(const v8s*)&ldsB[boff + (wn * 64 + ni * 16 + llo) * 32 + psw * 8];
        #pragma unroll
        for (int mi = 0; mi < 4; ++mi)
            #pragma unroll
            for (int ni = 0; ni < 4; ++ni)
                acc[mi][ni] = __builtin_amdgcn_mfma_f32_16x16x32_bf16(Af[mi], Bf[ni], acc[mi][ni], 0, 0, 0);
        __syncthreads();   // drains stage(kt+1); closes WAR window on buffers
    }

    // ---- epilogue: 2 phases of 64 rows (4 filter groups each) ----
    const int basew[6] = {0, 0, 1, 3, 6, 10};

    #pragma unroll
    for (int phase = 0; phase < 2; ++phase) {
        if (wm == phase) {
            // C/D layout: col = lane&15, row = quad*4 + reg  [verified m89/m91]
            #pragma unroll
            for (int mi = 0; mi < 4; ++mi)
                #pragma unroll
                for (int ni = 0; ni < 4; ++ni)
                    #pragma unroll
                    for (int r = 0; r < 4; ++r)
                        Gs[(mi * 16 + quad * 4 + r) * 129 + wn * 64 + ni * 16 + llo] = acc[mi][ni][r];
        }
        __syncthreads();
        // pooling: wave wid handles filter group fl = wid of this phase
        {
            int fl = wid;
            int f = mt * 8 + phase * 4 + fl;
            #pragma unroll
            for (int w = 1; w <= 5; ++w) {
                float bias = (w == 1 ? cb1 : w == 2 ? cb2 : w == 3 ? cb3 : w == 4 ? cb4 : cb5)[f];
                int limv = Leff - w + 1 - n0;          // tile-local validity bound
                float vmax = -1.f;
                #pragma unroll
                for (int half = 0; half < 2; ++half) {
                    int t = half * 64 + lane;
                    if (t <= 128 - w && t < limv) {
                        float s = 0.f;
                        #pragma unroll
                        for (int j = 0; j < w; ++j)
                            s += Gs[(fl * 16 + basew[w] + j) * 129 + t + j];
                        s += bias;
                        s = fmaxf(s, 0.f);
                        vmax = fmaxf(vmax, s);
                    }
                }
                #pragma unroll
                for (int off = 32; off >= 1; off >>= 1)
                    vmax = fmaxf(vmax, __shfl_xor(vmax, off));
                if (lane == 0 && vmax >= 0.f)
                    atomicMax((int*)&pools[(b * 5 + (w - 1)) * NFC + f], __float_as_int(vmax));
            }
        }
        __syncthreads();
    }
}

// ---------------------------------------------------------------------------
// Kernel 2: per-batch dot(feat, v) + c -> sigmoid.
// feat[b][k] = pools[b][w][f] with k = w*128+f (matches concat order).
// ---------------------------------------------------------------------------
__global__ void head(const float* __restrict__ pools, const float* __restrict__ v,
                     float* __restrict__ out) {
    int b = blockIdx.x;
    int tid = threadIdx.x;
    float s = 0.f;
    for (int k = tid; k < 640; k += 256) s += pools[b * 640 + k] * v[k];
    __shared__ float red[256];
    red[tid] = s;
    __syncthreads();
    for (int st = 128; st; st >>= 1) {
        if (tid < st) red[tid] += red[tid + st];
        __syncthreads();
    }
    if (tid == 0) out[b] = 1.f / (1.f + expf(-(red[0] + v[640])));
}

// ---------------------------------------------------------------------------
extern "C" void kernel_launch(void* const* d_in, const int* in_sizes, int n_in,
                              void* d_out, int out_size, void* d_ws, size_t ws_size,
                              hipStream_t stream) {
    const float* enc  = (const float*)d_in[0];
    const int* lens   = (const int*)d_in[1];
    const float* w1   = (const float*)d_in[2];
    const float* b1   = (const float*)d_in[3];
    const float* w2   = (const float*)d_in[4];
    const float* b2   = (const float*)d_in[5];
    const float* w3   = (const float*)d_in[6];
    const float* b3   = (const float*)d_in[7];
    const float* w4   = (const float*)d_in[8];
    const float* b4   = (const float*)d_in[9];
    const float* w5   = (const float*)d_in[10];
    const float* b5   = (const float*)d_in[11];
    const float* fc1w = (const float*)d_in[12];
    const float* fc1b = (const float*)d_in[13];
    const float* fc2w = (const float*)d_in[14];
    const float* fc2b = (const float*)d_in[15];
    float* out = (float*)d_out;

    // workspace layout
    unsigned short* Xg = (unsigned short*)d_ws;          // 33,554,432 ushorts (64 MB)
    unsigned short* Wg = Xg + 33554432;                  // 1,048,576 ushorts (2 MB)
    float* pools  = (float*)(Wg + 1048576);              // 81,920 floats
    float* vbuf   = pools + 81920;                       // 641 floats
    int* wlist    = (int*)(vbuf + 641);                  // 641 ints

    prep_all<<<12610, 256, 0, stream>>>(enc, lens, Xg, w1, w2, w3, w4, w5, Wg, pools,
                                        fc1w, fc1b, fc2w, fc2b, vbuf, wlist);
    conv_gemm<<<dim3(16, 640), 256, 0, stream>>>(Wg, Xg, lens, wlist, b1, b2, b3, b4, b5, pools);
    head<<<128, 256, 0, stream>>>(pools, vbuf, out);
}